// Round 7
// baseline (112.954 us; speedup 1.0000x reference)
//
#include <hip/hip_runtime.h>
#include <hip/hip_bf16.h>

typedef __attribute__((ext_vector_type(8))) short short8;
typedef __attribute__((ext_vector_type(4))) float f32x4;

#define M_TOTAL 131072
#define K_DIM 512
#define N_DIM 128
#define BM 128
#define BK 32
#define HALF 65536
#define GBLOCKS 1024
#define KSTEPS 16

// 32 bf16 = 64 B data + 16 B pad = 80 B rows (16B-aligned)
#define LDS_STRIDE 80
#define XTILE (BM * LDS_STRIDE)      // 10240 B
#define WTILE (N_DIM * LDS_STRIDE)   // 10240 B

__device__ __forceinline__ short bf16_bits(float f) {
    __hip_bfloat16 h = __float2bfloat16(f);
    return __builtin_bit_cast(short, h);
}

__device__ __forceinline__ short8 cvt8(f32x4 a, f32x4 b) {
    short8 p;
    p[0] = bf16_bits(a[0]); p[1] = bf16_bits(a[1]);
    p[2] = bf16_bits(a[2]); p[3] = bf16_bits(a[3]);
    p[4] = bf16_bits(b[0]); p[5] = bf16_bits(b[1]);
    p[6] = bf16_bits(b[2]); p[7] = bf16_bits(b[3]);
    return p;
}

// ---------------- W -> W^T bf16 prep ----------------------------------------
__global__ void __launch_bounds__(256) wt_prep_kernel(
    const float* __restrict__ W, __hip_bfloat16* __restrict__ Wt)
{
    int idx = blockIdx.x * 256 + threadIdx.x;   // 65536 total
    int k = idx >> 7;        // 0..511
    int n = idx & 127;       // 0..127
    Wt[n * K_DIM + k] = __float2bfloat16(W[idx]);
}

// ---- fused: relu(x@W+b), depth-2 x-prefetch MFMA core, + in-block MMD ------
// Block b owns first-half rows [64b,64b+64) (LDS rows 0..63) and second-half
// rows [HALF+64b, +64) (LDS rows 64..127). Tile t lives in regset (t&1).
__global__ void __launch_bounds__(256, 4) gemm_relu_mmd_kernel(
    const float* __restrict__ x, const __hip_bfloat16* __restrict__ Wt,
    const float* __restrict__ bias, float* __restrict__ out,
    double* __restrict__ partials)
{
    __shared__ char pool[2 * XTILE + 2 * WTILE];   // exactly 40960 B
    char* xa0 = pool;
    char* xa1 = pool + XTILE;
    char* wb0 = pool + 2 * XTILE;
    char* wb1 = pool + 2 * XTILE + WTILE;
    float* gsh = (float*)pool;   // reused after k-loop (xa dead by then)

    const int tid  = threadIdx.x;
    const int lane = tid & 63;
    const int wave = tid >> 6;          // 4 waves: 2x2 grid of 64x64 sub-tiles
    const int wrow = (wave & 1) * 64;
    const int wcol = (wave >> 1) * 64;
    const long blk = blockIdx.x;
    const long row0f = blk * 64;                 // first-half base
    const long row0s = (long)HALF + blk * 64;    // second-half base

    f32x4 acc[4][4];
#pragma unroll
    for (int m = 0; m < 4; ++m)
#pragma unroll
        for (int n = 0; n < 4; ++n) acc[m][n] = (f32x4)(0.0f);

    const int sr = tid >> 2;            // x stage row 0..63
    const int sc = (tid & 3) * 8;       // x stage col {0,8,16,24} (f32)
    const int wn = tid >> 1;            // Wt stage row 0..127
    const int wk = (tid & 1) * 16;      // Wt stage k {0,16} (bf16)

    const int frow = lane & 15;
    const int kg   = (lane >> 4) * 8;

    const float* xsrc0 = x + (row0f + sr) * (long)K_DIM + sc;   // LDS rows 0..63
    const float* xsrc1 = x + (row0s + sr) * (long)K_DIM + sc;   // LDS rows 64..127
    const __hip_bfloat16* wsrc = Wt + (long)wn * K_DIM + wk;

    f32x4 ra0, ra1, ra2, ra3;   // regset A (odd tiles)
    f32x4 rb0, rb1, rb2, rb3;   // regset B (even tiles)
    short8 rw0, rw1;

#define ISSUE_X(R, kt) do { \
        R##0 = *(const f32x4*)(xsrc0 + (kt)); \
        R##1 = *(const f32x4*)(xsrc0 + (kt) + 4); \
        R##2 = *(const f32x4*)(xsrc1 + (kt)); \
        R##3 = *(const f32x4*)(xsrc1 + (kt) + 4); \
    } while (0)

    // ---- prologue: t0 -> rb, t1 -> ra; stage t0 into buffer 0 ----
    ISSUE_X(rb, 0);
    ISSUE_X(ra, BK);
    rw0 = *(const short8*)(wsrc);
    rw1 = *(const short8*)(wsrc + 8);
    *(short8*)(xa0 + sr * LDS_STRIDE + sc * 2)        = cvt8(rb0, rb1);
    *(short8*)(xa0 + (sr + 64) * LDS_STRIDE + sc * 2) = cvt8(rb2, rb3);
    {
        char* wd = wb0 + wn * LDS_STRIDE + wk * 2;
        *(short8*)(wd)      = rw0;
        *(short8*)(wd + 16) = rw1;
    }
    __syncthreads();

    // STEP(K): compute LDS[K&1]; RN holds tile K+1 (written at bottom);
    // RI receives tile K+2 (issued at top).
#define STEP(K, RN, RI, XCUR, XNXT, WCUR, WNXT) do { \
        if ((K) + 2 < KSTEPS) ISSUE_X(RI, ((K) + 2) * BK); \
        if ((K) + 1 < KSTEPS) { \
            rw0 = *(const short8*)(wsrc + ((K) + 1) * BK); \
            rw1 = *(const short8*)(wsrc + ((K) + 1) * BK + 8); \
        } \
        short8 af[4], bfv[4]; \
        _Pragma("unroll") \
        for (int m = 0; m < 4; ++m) { \
            const int r = wrow + m * 16 + frow; \
            af[m] = *(const short8*)(XCUR + r * LDS_STRIDE + kg * 2); \
        } \
        _Pragma("unroll") \
        for (int n = 0; n < 4; ++n) { \
            const int r = wcol + n * 16 + frow; \
            bfv[n] = *(const short8*)(WCUR + r * LDS_STRIDE + kg * 2); \
        } \
        _Pragma("unroll") \
        for (int m = 0; m < 4; ++m) \
            _Pragma("unroll") \
            for (int n = 0; n < 4; ++n) \
                acc[m][n] = __builtin_amdgcn_mfma_f32_16x16x32_bf16( \
                    af[m], bfv[n], acc[m][n], 0, 0, 0); \
        if ((K) + 1 < KSTEPS) { \
            *(short8*)(XNXT + sr * LDS_STRIDE + sc * 2)        = cvt8(RN##0, RN##1); \
            *(short8*)(XNXT + (sr + 64) * LDS_STRIDE + sc * 2) = cvt8(RN##2, RN##3); \
            char* wd = WNXT + wn * LDS_STRIDE + wk * 2; \
            *(short8*)(wd)      = rw0; \
            *(short8*)(wd + 16) = rw1; \
        } \
        __syncthreads(); \
    } while (0)

    for (int k = 0; k < KSTEPS; k += 2) {
        STEP(k,     ra, rb, xa0, xa1, wb0, wb1);
        STEP(k + 1, rb, ra, xa1, xa0, wb1, wb0);
    }
#undef STEP
#undef ISSUE_X

    // epilogue: bias + relu + store (C/D: col=lane&15, row=(lane>>4)*4+reg)
    float bv[4];
#pragma unroll
    for (int n = 0; n < 4; ++n) bv[n] = bias[wcol + n * 16 + frow];
    const int colb = wcol + frow;
    const long wbase = (wrow == 0) ? row0f : (row0s - 64);
    const long rowb = wbase + wrow + ((lane >> 4) * 4);
#pragma unroll
    for (int m = 0; m < 4; ++m)
#pragma unroll
        for (int j = 0; j < 4; ++j) {
            float* orow = out + (rowb + m * 16 + j) * N_DIM;
#pragma unroll
            for (int n = 0; n < 4; ++n)
                orow[colb + n * 16] = fmaxf(acc[m][n][j] + bv[n], 0.0f);
        }

    // ---- in-block MMD over the 32 pairs this block owns (L2-hot re-read) ---
    __threadfence_block();
    __syncthreads();

    const int pr  = tid >> 3;      // pair 0..31
    const int sub = tid & 7;       // 8 threads/pair, 16 dims each
    const float* r0 = out + (row0f + 2 * pr) * (long)N_DIM + sub * 16;  // s0
    const float* r1 = r0 + N_DIM;                                       // s1
    const float* r2 = out + (row0s + 2 * pr) * (long)N_DIM + sub * 16;  // t0
    const float* r3 = r2 + N_DIM;                                       // t1

    f32x4 vss = (f32x4)(0.f), vtt = (f32x4)(0.f), vst = (f32x4)(0.f), vts = (f32x4)(0.f);
#pragma unroll
    for (int c = 0; c < 4; ++c) {
        f32x4 a0 = *(const f32x4*)(r0 + 4 * c);
        f32x4 a1 = *(const f32x4*)(r1 + 4 * c);
        f32x4 b0 = *(const f32x4*)(r2 + 4 * c);
        f32x4 b1 = *(const f32x4*)(r3 + 4 * c);
        f32x4 d;
        d = a0 - a1; vss += d * d;
        d = b0 - b1; vtt += d * d;
        d = a0 - b1; vst += d * d;
        d = a1 - b0; vts += d * d;
    }
    float D[4];
    D[0] = vss[0] + vss[1] + vss[2] + vss[3];
    D[1] = vtt[0] + vtt[1] + vtt[2] + vtt[3];
    D[2] = vst[0] + vst[1] + vst[2] + vst[3];
    D[3] = vts[0] + vts[1] + vts[2] + vts[3];
#pragma unroll
    for (int off = 1; off <= 4; off <<= 1) {
#pragma unroll
        for (int i = 0; i < 4; ++i) D[i] += __shfl_xor(D[i], off, 64);
    }
    // 32 signed exp terms spread over the 8 threads of the pair (4 each)
    float part = 0.f;
#pragma unroll
    for (int j = 0; j < 4; ++j) {
        const int t  = sub * 4 + j;
        const int di = t >> 3;           // distance index 0..3
        const float invg = 16.0f / (float)(1 << (t & 7));   // 1/gamma_k
        const float e = __expf(-D[di] * invg);
        part += (di < 2) ? e : -e;
    }
#pragma unroll
    for (int off = 1; off <= 4; off <<= 1) part += __shfl_xor(part, off, 64);
    if (sub == 0) gsh[pr] = part * 0.125f;
    __syncthreads();
    if (tid == 0) {
        double s = 0.0;
#pragma unroll
        for (int i = 0; i < 32; ++i) s += (double)gsh[i];
        partials[blk] = s;
    }
}

__global__ void __launch_bounds__(256) mmd_reduce_kernel(
    const double* __restrict__ partials, float* __restrict__ loss)
{
    __shared__ double sd[256];
    const int tid = threadIdx.x;
    double s = 0.0;
    for (int i = tid; i < GBLOCKS; i += 256) s += partials[i];
    sd[tid] = s;
    __syncthreads();
    for (int w = 128; w; w >>= 1) {
        if (tid < w) sd[tid] += sd[tid + w];
        __syncthreads();
    }
    if (tid == 0) loss[0] = (float)(sd[0] * (2.0 / 65536.0));
}

extern "C" void kernel_launch(void* const* d_in, const int* in_sizes, int n_in,
                              void* d_out, int out_size, void* d_ws, size_t ws_size,
                              hipStream_t stream) {
    const float* x = (const float*)d_in[0];
    const float* W = (const float*)d_in[1];
    const float* b = (const float*)d_in[2];
    float* out = (float*)d_out;                         // 131072*128 + 1 floats

    __hip_bfloat16* Wt = (__hip_bfloat16*)d_ws;                 // 128 KB
    double* partials = (double*)((char*)d_ws + 131072);         // 8 KB

    wt_prep_kernel<<<256, 256, 0, stream>>>(W, Wt);
    gemm_relu_mmd_kernel<<<GBLOCKS, 256, 0, stream>>>(x, Wt, b, out, partials);
    mmd_reduce_kernel<<<1, 256, 0, stream>>>(partials, out + (long)M_TOTAL * N_DIM);
}

// Round 8
// 100.937 us; speedup vs baseline: 1.1191x; 1.1191x over previous
//
#include <hip/hip_runtime.h>
#include <hip/hip_bf16.h>

typedef __attribute__((ext_vector_type(8))) short short8;
typedef __attribute__((ext_vector_type(4))) float f32x4;

#define M_TOTAL 131072
#define K_DIM 512
#define N_DIM 128
#define BM 128
#define BK 32
#define HALF 65536
#define GBLOCKS 1024
#define KSTEPS 16

// 32 bf16 = 64 B data + 16 B pad = 80 B rows (16B-aligned)
#define LDS_STRIDE 80
#define XTILE (BM * LDS_STRIDE)      // 10240 B
#define WTILE (N_DIM * LDS_STRIDE)   // 10240 B

__device__ __forceinline__ short bf16_bits(float f) {
    __hip_bfloat16 h = __float2bfloat16(f);
    return __builtin_bit_cast(short, h);
}

__device__ __forceinline__ short8 cvt8(f32x4 a, f32x4 b) {
    short8 p;
    p[0] = bf16_bits(a[0]); p[1] = bf16_bits(a[1]);
    p[2] = bf16_bits(a[2]); p[3] = bf16_bits(a[3]);
    p[4] = bf16_bits(b[0]); p[5] = bf16_bits(b[1]);
    p[6] = bf16_bits(b[2]); p[7] = bf16_bits(b[3]);
    return p;
}

// ---------------- W -> W^T bf16 prep ----------------------------------------
__global__ void __launch_bounds__(256) wt_prep_kernel(
    const float* __restrict__ W, __hip_bfloat16* __restrict__ Wt)
{
    int idx = blockIdx.x * 256 + threadIdx.x;   // 65536 total
    int k = idx >> 7;        // 0..511
    int n = idx & 127;       // 0..127
    Wt[n * K_DIM + k] = __float2bfloat16(W[idx]);
}

// ---- fused: relu(x@W+b), R6 depth-1 double-buffered core, + in-block MMD ---
// LDS pool is exactly 40960 B (gsh aliased into dead x-tile space) and
// __launch_bounds__(256,4) pins VGPR<=128 -> 4 blocks/CU (16 waves).
__global__ void __launch_bounds__(256, 4) gemm_relu_mmd_kernel(
    const float* __restrict__ x, const __hip_bfloat16* __restrict__ Wt,
    const float* __restrict__ bias, float* __restrict__ out,
    double* __restrict__ partials)
{
    __shared__ char pool[2 * XTILE + 2 * WTILE];   // exactly 40960 B
    char* xa = pool;                  // xa tile t at pool + (t&1)*XTILE
    char* wb = pool + 2 * XTILE;      // wb tile t at wb   + (t&1)*WTILE
    float* gsh = (float*)pool;        // reused after k-loop (xa dead by then)

    const int tid  = threadIdx.x;
    const int lane = tid & 63;
    const int wave = tid >> 6;          // 4 waves: 2x2 grid of 64x64 sub-tiles
    const int wrow = (wave & 1) * 64;
    const int wcol = (wave >> 1) * 64;
    const long blk = blockIdx.x;
    const long row0f = blk * 64;                 // first-half base
    const long row0s = (long)HALF + blk * 64;    // second-half base

    f32x4 acc[4][4];
#pragma unroll
    for (int m = 0; m < 4; ++m)
#pragma unroll
        for (int n = 0; n < 4; ++n) acc[m][n] = (f32x4)(0.0f);

    const int sr = tid >> 2;            // x stage row 0..63
    const int sc = (tid & 3) * 8;       // x stage col {0,8,16,24} (f32)
    const int wn = tid >> 1;            // Wt stage row 0..127
    const int wk = (tid & 1) * 16;      // Wt stage k {0,16} (bf16)

    const int frow = lane & 15;
    const int kg   = (lane >> 4) * 8;

    const float* xsrc0 = x + (row0f + sr) * (long)K_DIM + sc;   // LDS rows 0..63
    const float* xsrc1 = x + (row0s + sr) * (long)K_DIM + sc;   // LDS rows 64..127
    const __hip_bfloat16* wsrc = Wt + (long)wn * K_DIM + wk;

    // ---- prologue: stage tile 0 into buffer 0 ----
    f32x4 r00 = *(const f32x4*)(xsrc0);
    f32x4 r01 = *(const f32x4*)(xsrc0 + 4);
    f32x4 r10 = *(const f32x4*)(xsrc1);
    f32x4 r11 = *(const f32x4*)(xsrc1 + 4);
    short8 rw0 = *(const short8*)(wsrc);
    short8 rw1 = *(const short8*)(wsrc + 8);

    *(short8*)(xa + sr * LDS_STRIDE + sc * 2)        = cvt8(r00, r01);
    *(short8*)(xa + (sr + 64) * LDS_STRIDE + sc * 2) = cvt8(r10, r11);
    {
        char* wd = wb + wn * LDS_STRIDE + wk * 2;
        *(short8*)(wd)      = rw0;
        *(short8*)(wd + 16) = rw1;
    }
    __syncthreads();

    for (int k = 0; k < KSTEPS; ++k) {
        char* xcur = xa + (k & 1) * XTILE;
        char* xnxt = xa + ((k & 1) ^ 1) * XTILE;
        char* wcur = wb + (k & 1) * WTILE;
        char* wnxt = wb + ((k & 1) ^ 1) * WTILE;
        const int kt = (k + 1) * BK;

        // issue next tile's global loads (in flight during compute)
        if (k < KSTEPS - 1) {
            r00 = *(const f32x4*)(xsrc0 + kt);
            r01 = *(const f32x4*)(xsrc0 + kt + 4);
            r10 = *(const f32x4*)(xsrc1 + kt);
            r11 = *(const f32x4*)(xsrc1 + kt + 4);
            rw0 = *(const short8*)(wsrc + kt);
            rw1 = *(const short8*)(wsrc + kt + 8);
        }

        // compute current tile
        short8 af[4], bfv[4];
#pragma unroll
        for (int m = 0; m < 4; ++m) {
            const int r = wrow + m * 16 + frow;
            af[m] = *(const short8*)(xcur + r * LDS_STRIDE + kg * 2);
        }
#pragma unroll
        for (int n = 0; n < 4; ++n) {
            const int r = wcol + n * 16 + frow;
            bfv[n] = *(const short8*)(wcur + r * LDS_STRIDE + kg * 2);
        }
#pragma unroll
        for (int m = 0; m < 4; ++m)
#pragma unroll
            for (int n = 0; n < 4; ++n)
                acc[m][n] = __builtin_amdgcn_mfma_f32_16x16x32_bf16(
                    af[m], bfv[n], acc[m][n], 0, 0, 0);

        // stage next tile into alternate buffer
        if (k < KSTEPS - 1) {
            *(short8*)(xnxt + sr * LDS_STRIDE + sc * 2)        = cvt8(r00, r01);
            *(short8*)(xnxt + (sr + 64) * LDS_STRIDE + sc * 2) = cvt8(r10, r11);
            char* wd = wnxt + wn * LDS_STRIDE + wk * 2;
            *(short8*)(wd)      = rw0;
            *(short8*)(wd + 16) = rw1;
        }
        __syncthreads();
    }

    // epilogue: bias + relu + store (C/D: col=lane&15, row=(lane>>4)*4+reg)
    float bv[4];
#pragma unroll
    for (int n = 0; n < 4; ++n) bv[n] = bias[wcol + n * 16 + frow];
    const int colb = wcol + frow;
    const long wbase = (wrow == 0) ? row0f : (row0s - 64);
    const long rowb = wbase + wrow + ((lane >> 4) * 4);
#pragma unroll
    for (int m = 0; m < 4; ++m)
#pragma unroll
        for (int j = 0; j < 4; ++j) {
            float* orow = out + (rowb + m * 16 + j) * N_DIM;
#pragma unroll
            for (int n = 0; n < 4; ++n)
                orow[colb + n * 16] = fmaxf(acc[m][n][j] + bv[n], 0.0f);
        }

    // ---- in-block MMD over the 32 pairs this block owns (L2-hot re-read) ---
    __threadfence_block();
    __syncthreads();

    const int pr  = tid >> 3;      // pair 0..31
    const int sub = tid & 7;       // 8 threads/pair, 16 dims each
    const float* r0 = out + (row0f + 2 * pr) * (long)N_DIM + sub * 16;  // s0
    const float* r1 = r0 + N_DIM;                                       // s1
    const float* r2 = out + (row0s + 2 * pr) * (long)N_DIM + sub * 16;  // t0
    const float* r3 = r2 + N_DIM;                                       // t1

    f32x4 vss = (f32x4)(0.f), vtt = (f32x4)(0.f), vst = (f32x4)(0.f), vts = (f32x4)(0.f);
#pragma unroll
    for (int c = 0; c < 4; ++c) {
        f32x4 a0 = *(const f32x4*)(r0 + 4 * c);
        f32x4 a1 = *(const f32x4*)(r1 + 4 * c);
        f32x4 b0 = *(const f32x4*)(r2 + 4 * c);
        f32x4 b1 = *(const f32x4*)(r3 + 4 * c);
        f32x4 d;
        d = a0 - a1; vss += d * d;
        d = b0 - b1; vtt += d * d;
        d = a0 - b1; vst += d * d;
        d = a1 - b0; vts += d * d;
    }
    float D[4];
    D[0] = vss[0] + vss[1] + vss[2] + vss[3];
    D[1] = vtt[0] + vtt[1] + vtt[2] + vtt[3];
    D[2] = vst[0] + vst[1] + vst[2] + vst[3];
    D[3] = vts[0] + vts[1] + vts[2] + vts[3];
#pragma unroll
    for (int off = 1; off <= 4; off <<= 1) {
#pragma unroll
        for (int i = 0; i < 4; ++i) D[i] += __shfl_xor(D[i], off, 64);
    }
    // 32 signed exp terms spread over the 8 threads of the pair (4 each)
    float part = 0.f;
#pragma unroll
    for (int j = 0; j < 4; ++j) {
        const int t  = sub * 4 + j;
        const int di = t >> 3;           // distance index 0..3
        const float invg = 16.0f / (float)(1 << (t & 7));   // 1/gamma_k
        const float e = __expf(-D[di] * invg);
        part += (di < 2) ? e : -e;
    }
#pragma unroll
    for (int off = 1; off <= 4; off <<= 1) part += __shfl_xor(part, off, 64);
    if (sub == 0) gsh[pr] = part * 0.125f;
    __syncthreads();
    if (tid == 0) {
        double s = 0.0;
#pragma unroll
        for (int i = 0; i < 32; ++i) s += (double)gsh[i];
        partials[blk] = s;
    }
}

__global__ void __launch_bounds__(256) mmd_reduce_kernel(
    const double* __restrict__ partials, float* __restrict__ loss)
{
    __shared__ double sd[256];
    const int tid = threadIdx.x;
    double s = 0.0;
    for (int i = tid; i < GBLOCKS; i += 256) s += partials[i];
    sd[tid] = s;
    __syncthreads();
    for (int w = 128; w; w >>= 1) {
        if (tid < w) sd[tid] += sd[tid + w];
        __syncthreads();
    }
    if (tid == 0) loss[0] = (float)(sd[0] * (2.0 / 65536.0));
}

extern "C" void kernel_launch(void* const* d_in, const int* in_sizes, int n_in,
                              void* d_out, int out_size, void* d_ws, size_t ws_size,
                              hipStream_t stream) {
    const float* x = (const float*)d_in[0];
    const float* W = (const float*)d_in[1];
    const float* b = (const float*)d_in[2];
    float* out = (float*)d_out;                         // 131072*128 + 1 floats

    __hip_bfloat16* Wt = (__hip_bfloat16*)d_ws;                 // 128 KB
    double* partials = (double*)((char*)d_ws + 131072);         // 8 KB

    wt_prep_kernel<<<256, 256, 0, stream>>>(W, Wt);
    gemm_relu_mmd_kernel<<<GBLOCKS, 256, 0, stream>>>(x, Wt, b, out, partials);
    mmd_reduce_kernel<<<1, 256, 0, stream>>>(partials, out + (long)M_TOTAL * N_DIM);
}

// Round 9
// 95.934 us; speedup vs baseline: 1.1774x; 1.0521x over previous
//
#include <hip/hip_runtime.h>
#include <hip/hip_bf16.h>

typedef __attribute__((ext_vector_type(8))) short short8;
typedef __attribute__((ext_vector_type(4))) float f32x4;

#define M_TOTAL 131072
#define K_DIM 512
#define N_DIM 128
#define BM 128
#define BK 32
#define HALF 65536
#define GBLOCKS 1024
#define KSTEPS 16

// x tile: padded 80 B rows (reg-staged, padding allowed)
#define LDS_STRIDE 80
#define XTILE (BM * LDS_STRIDE)      // 10240 B
// W tile: LINEAR 64 B rows (global_load_lds requires contiguous dest)
#define WROW 64
#define WTILE (N_DIM * WROW)         // 8192 B

__device__ __forceinline__ short bf16_bits(float f) {
    __hip_bfloat16 h = __float2bfloat16(f);
    return __builtin_bit_cast(short, h);
}

__device__ __forceinline__ short8 cvt8(f32x4 a, f32x4 b) {
    short8 p;
    p[0] = bf16_bits(a[0]); p[1] = bf16_bits(a[1]);
    p[2] = bf16_bits(a[2]); p[3] = bf16_bits(a[3]);
    p[4] = bf16_bits(b[0]); p[5] = bf16_bits(b[1]);
    p[6] = bf16_bits(b[2]); p[7] = bf16_bits(b[3]);
    return p;
}

// ---------------- W -> W^T bf16 prep ----------------------------------------
__global__ void __launch_bounds__(256) wt_prep_kernel(
    const float* __restrict__ W, __hip_bfloat16* __restrict__ Wt)
{
    int idx = blockIdx.x * 256 + threadIdx.x;   // 65536 total
    int k = idx >> 7;        // 0..511
    int n = idx & 127;       // 0..127
    Wt[n * K_DIM + k] = __float2bfloat16(W[idx]);
}

// ---- fused: relu(x@W+b); depth-1 dbuf core, W via global_load_lds ----------
// Block b owns first-half rows [64b,64b+64) (LDS rows 0..63) and second-half
// rows [HALF+64b,+64) (LDS rows 64..127).
__global__ void gemm_relu_mmd_kernel(
    const float* __restrict__ x, const __hip_bfloat16* __restrict__ Wt,
    const float* __restrict__ bias, float* __restrict__ out,
    double* __restrict__ partials)
{
    __shared__ char pool[2 * XTILE + 2 * WTILE];   // 36864 B
    char* xa = pool;                  // x tile t at pool + (t&1)*XTILE
    char* wb = pool + 2 * XTILE;      // W tile t at wb   + (t&1)*WTILE
    float* gsh = (float*)pool;        // reused after k-loop (xa dead by then)

    const int tid  = threadIdx.x;
    const int lane = tid & 63;
    const int wave = tid >> 6;          // 4 waves: 2x2 grid of 64x64 sub-tiles
    const int wrow = (wave & 1) * 64;
    const int wcol = (wave >> 1) * 64;
    const long blk = blockIdx.x;
    const long row0f = blk * 64;                 // first-half base
    const long row0s = (long)HALF + blk * 64;    // second-half base

    f32x4 acc[4][4];
#pragma unroll
    for (int m = 0; m < 4; ++m)
#pragma unroll
        for (int n = 0; n < 4; ++n) acc[m][n] = (f32x4)(0.0f);

    const int sr = tid >> 2;            // x stage row 0..63
    const int sc = (tid & 3) * 8;       // x stage col {0,8,16,24} (f32)

    const int frow = lane & 15;
    const int kg   = (lane >> 4) * 8;

    const float* xsrc0 = x + (row0f + sr) * (long)K_DIM + sc;   // LDS rows 0..63
    const float* xsrc1 = x + (row0s + sr) * (long)K_DIM + sc;   // LDS rows 64..127

    // W async staging: wave w covers rows w*16..w*16+15 (+64 for 2nd chunk),
    // lane's 16 B = row w*16+(lane>>2), byte (lane&3)*16 of the 64 B row.
    const __hip_bfloat16* wg_base =
        Wt + (long)(wave * 16 + (lane >> 2)) * K_DIM + (lane & 3) * 8;

#define ISSUE_W(buf, kt) do { \
        __builtin_amdgcn_global_load_lds( \
            (const __attribute__((address_space(1))) void*)(wg_base + (kt)), \
            (__attribute__((address_space(3))) void*)((buf) + wave * 1024), \
            16, 0, 0); \
        __builtin_amdgcn_global_load_lds( \
            (const __attribute__((address_space(1))) void*)(wg_base + 64 * K_DIM + (kt)), \
            (__attribute__((address_space(3))) void*)((buf) + 4096 + wave * 1024), \
            16, 0, 0); \
    } while (0)

    // ---- prologue: stage tile 0 ----
    ISSUE_W(wb, 0);
    f32x4 r00 = *(const f32x4*)(xsrc0);
    f32x4 r01 = *(const f32x4*)(xsrc0 + 4);
    f32x4 r10 = *(const f32x4*)(xsrc1);
    f32x4 r11 = *(const f32x4*)(xsrc1 + 4);
    *(short8*)(xa + sr * LDS_STRIDE + sc * 2)        = cvt8(r00, r01);
    *(short8*)(xa + (sr + 64) * LDS_STRIDE + sc * 2) = cvt8(r10, r11);
    __syncthreads();   // drains vmcnt (async W) + lgkm (x writes)

    for (int k = 0; k < KSTEPS; ++k) {
        char* xcur = xa + (k & 1) * XTILE;
        char* xnxt = xa + ((k & 1) ^ 1) * XTILE;
        char* wcur = wb + (k & 1) * WTILE;
        char* wnxt = wb + ((k & 1) ^ 1) * WTILE;
        const int kt = (k + 1) * BK;

        // issue next tile's loads (W async -> LDS, x -> regs)
        if (k < KSTEPS - 1) {
            ISSUE_W(wnxt, kt);
            r00 = *(const f32x4*)(xsrc0 + kt);
            r01 = *(const f32x4*)(xsrc0 + kt + 4);
            r10 = *(const f32x4*)(xsrc1 + kt);
            r11 = *(const f32x4*)(xsrc1 + kt + 4);
        }

        // compute current tile
        short8 af[4], bfv[4];
#pragma unroll
        for (int m = 0; m < 4; ++m) {
            const int r = wrow + m * 16 + frow;
            af[m] = *(const short8*)(xcur + r * LDS_STRIDE + kg * 2);
        }
#pragma unroll
        for (int n = 0; n < 4; ++n) {
            const int r = wcol + n * 16 + frow;
            bfv[n] = *(const short8*)(wcur + r * WROW + kg * 2);
        }
#pragma unroll
        for (int m = 0; m < 4; ++m)
#pragma unroll
            for (int n = 0; n < 4; ++n)
                acc[m][n] = __builtin_amdgcn_mfma_f32_16x16x32_bf16(
                    af[m], bfv[n], acc[m][n], 0, 0, 0);

        // stage next x tile into alternate buffer
        if (k < KSTEPS - 1) {
            *(short8*)(xnxt + sr * LDS_STRIDE + sc * 2)        = cvt8(r00, r01);
            *(short8*)(xnxt + (sr + 64) * LDS_STRIDE + sc * 2) = cvt8(r10, r11);
        }
        __syncthreads();
    }
#undef ISSUE_W

    // epilogue: bias + relu + store (C/D: col=lane&15, row=(lane>>4)*4+reg)
    float bv[4];
#pragma unroll
    for (int n = 0; n < 4; ++n) bv[n] = bias[wcol + n * 16 + frow];
    const int colb = wcol + frow;
    const long wbase = (wrow == 0) ? row0f : (row0s - 64);
    const long rowb = wbase + wrow + ((lane >> 4) * 4);
#pragma unroll
    for (int m = 0; m < 4; ++m)
#pragma unroll
        for (int j = 0; j < 4; ++j) {
            float* orow = out + (rowb + m * 16 + j) * N_DIM;
#pragma unroll
            for (int n = 0; n < 4; ++n)
                orow[colb + n * 16] = fmaxf(acc[m][n][j] + bv[n], 0.0f);
        }

    // ---- in-block MMD over the 32 pairs this block owns (L2-hot re-read) ---
    __threadfence_block();
    __syncthreads();

    const int pr  = tid >> 3;      // pair 0..31
    const int sub = tid & 7;       // 8 threads/pair, 16 dims each
    const float* r0 = out + (row0f + 2 * pr) * (long)N_DIM + sub * 16;  // s0
    const float* r1 = r0 + N_DIM;                                       // s1
    const float* r2 = out + (row0s + 2 * pr) * (long)N_DIM + sub * 16;  // t0
    const float* r3 = r2 + N_DIM;                                       // t1

    f32x4 vss = (f32x4)(0.f), vtt = (f32x4)(0.f), vst = (f32x4)(0.f), vts = (f32x4)(0.f);
#pragma unroll
    for (int c = 0; c < 4; ++c) {
        f32x4 a0 = *(const f32x4*)(r0 + 4 * c);
        f32x4 a1 = *(const f32x4*)(r1 + 4 * c);
        f32x4 b0 = *(const f32x4*)(r2 + 4 * c);
        f32x4 b1 = *(const f32x4*)(r3 + 4 * c);
        f32x4 d;
        d = a0 - a1; vss += d * d;
        d = b0 - b1; vtt += d * d;
        d = a0 - b1; vst += d * d;
        d = a1 - b0; vts += d * d;
    }
    float D[4];
    D[0] = vss[0] + vss[1] + vss[2] + vss[3];
    D[1] = vtt[0] + vtt[1] + vtt[2] + vtt[3];
    D[2] = vst[0] + vst[1] + vst[2] + vst[3];
    D[3] = vts[0] + vts[1] + vts[2] + vts[3];
#pragma unroll
    for (int off = 1; off <= 4; off <<= 1) {
#pragma unroll
        for (int i = 0; i < 4; ++i) D[i] += __shfl_xor(D[i], off, 64);
    }
    // 32 signed exp terms spread over the 8 threads of the pair (4 each)
    float part = 0.f;
#pragma unroll
    for (int j = 0; j < 4; ++j) {
        const int t  = sub * 4 + j;
        const int di = t >> 3;           // distance index 0..3
        const float invg = 16.0f / (float)(1 << (t & 7));   // 1/gamma_k
        const float e = __expf(-D[di] * invg);
        part += (di < 2) ? e : -e;
    }
#pragma unroll
    for (int off = 1; off <= 4; off <<= 1) part += __shfl_xor(part, off, 64);
    if (sub == 0) gsh[pr] = part * 0.125f;
    __syncthreads();
    if (tid == 0) {
        double s = 0.0;
#pragma unroll
        for (int i = 0; i < 32; ++i) s += (double)gsh[i];
        partials[blk] = s;
    }
}

__global__ void __launch_bounds__(256) mmd_reduce_kernel(
    const double* __restrict__ partials, float* __restrict__ loss)
{
    __shared__ double sd[256];
    const int tid = threadIdx.x;
    double s = 0.0;
    for (int i = tid; i < GBLOCKS; i += 256) s += partials[i];
    sd[tid] = s;
    __syncthreads();
    for (int w = 128; w; w >>= 1) {
        if (tid < w) sd[tid] += sd[tid + w];
        __syncthreads();
    }
    if (tid == 0) loss[0] = (float)(sd[0] * (2.0 / 65536.0));
}

extern "C" void kernel_launch(void* const* d_in, const int* in_sizes, int n_in,
                              void* d_out, int out_size, void* d_ws, size_t ws_size,
                              hipStream_t stream) {
    const float* x = (const float*)d_in[0];
    const float* W = (const float*)d_in[1];
    const float* b = (const float*)d_in[2];
    float* out = (float*)d_out;                         // 131072*128 + 1 floats

    __hip_bfloat16* Wt = (__hip_bfloat16*)d_ws;                 // 128 KB
    double* partials = (double*)((char*)d_ws + 131072);         // 8 KB

    wt_prep_kernel<<<256, 256, 0, stream>>>(W, Wt);
    gemm_relu_mmd_kernel<<<GBLOCKS, 256, 0, stream>>>(x, Wt, b, out, partials);
    mmd_reduce_kernel<<<1, 256, 0, stream>>>(partials, out + (long)M_TOTAL * N_DIM);
}

// Round 10
// 90.827 us; speedup vs baseline: 1.2436x; 1.0562x over previous
//
#include <hip/hip_runtime.h>
#include <hip/hip_bf16.h>

typedef __attribute__((ext_vector_type(8))) short short8;
typedef __attribute__((ext_vector_type(4))) float f32x4;

#define M_TOTAL 131072
#define K_DIM 512
#define N_DIM 128
#define BM 128
#define BK 32
#define HALF 65536
#define GBLOCKS 1024
#define KSTEPS 16

// 32 bf16 = 64 B data + 16 B pad = 80 B rows (16B-aligned)
#define LDS_STRIDE 80
#define XTILE (BM * LDS_STRIDE)      // 10240 B
#define WTILE (N_DIM * LDS_STRIDE)   // 10240 B

__device__ __forceinline__ short bf16_bits(float f) {
    __hip_bfloat16 h = __float2bfloat16(f);
    return __builtin_bit_cast(short, h);
}

__device__ __forceinline__ short8 cvt8(f32x4 a, f32x4 b) {
    short8 p;
    p[0] = bf16_bits(a[0]); p[1] = bf16_bits(a[1]);
    p[2] = bf16_bits(a[2]); p[3] = bf16_bits(a[3]);
    p[4] = bf16_bits(b[0]); p[5] = bf16_bits(b[1]);
    p[6] = bf16_bits(b[2]); p[7] = bf16_bits(b[3]);
    return p;
}

// ---------------- W -> W^T bf16 prep ----------------------------------------
__global__ void __launch_bounds__(256) wt_prep_kernel(
    const float* __restrict__ W, __hip_bfloat16* __restrict__ Wt)
{
    int idx = blockIdx.x * 256 + threadIdx.x;   // 65536 total
    int k = idx >> 7;        // 0..511
    int n = idx & 127;       // 0..127
    Wt[n * K_DIM + k] = __float2bfloat16(W[idx]);
}

// ---- fused: relu(x@W+b) + in-block MMD; 8 waves x (32x64) sub-tiles --------
// Low-VGPR variant of the R6 core: acc 2x4 per wave, one x-chunk + one
// W-chunk staged per thread -> natural VGPR < 128 -> 4 waves/SIMD.
// Block b: first-half rows [64b,64b+64) = LDS rows 0..63, second-half rows
// [HALF+64b,+64) = LDS rows 64..127.
__global__ void __launch_bounds__(512, 4) gemm_relu_mmd_kernel(
    const float* __restrict__ x, const __hip_bfloat16* __restrict__ Wt,
    const float* __restrict__ bias, float* __restrict__ out,
    double* __restrict__ partials)
{
    __shared__ char pool[2 * XTILE + 2 * WTILE];   // exactly 40960 B
    char* xa = pool;                  // x tile t at pool + (t&1)*XTILE
    char* wb = pool + 2 * XTILE;      // W tile t at wb   + (t&1)*WTILE
    float* gsh = (float*)pool;        // reused after k-loop (xa dead by then)

    const int tid  = threadIdx.x;
    const int lane = tid & 63;
    const int wave = tid >> 6;          // 0..7: 4 row-groups x 2 col-groups
    const int wrow = (wave & 3) * 32;   // local rows wrow..wrow+31
    const int wcol = (wave >> 2) * 64;  // cols wcol..wcol+63
    const long blk = blockIdx.x;
    const long row0f = blk * 64;                 // first-half base
    const long row0s = (long)HALF + blk * 64;    // second-half base

    f32x4 acc[2][4];
#pragma unroll
    for (int m = 0; m < 2; ++m)
#pragma unroll
        for (int n = 0; n < 4; ++n) acc[m][n] = (f32x4)(0.0f);

    // staging: 512 threads cover 128 rows x 32 cols; thread -> row tid>>2,
    // f32-chunk (tid&3)*8 (x) / bf16-chunk (tid&3)*8 (Wt)
    const int sr  = tid >> 2;           // 0..127
    const int sby = (tid & 3) * 16;     // byte offset in 64B row window
    const long gr = (sr < 64) ? (row0f + sr) : (row0s + sr - 64);
    const float* xsrc = x + gr * (long)K_DIM + (tid & 3) * 8;
    const __hip_bfloat16* wsrc = Wt + (long)sr * K_DIM + (tid & 3) * 8;

    const int frow = lane & 15;
    const int kg   = (lane >> 4) * 8;

    // ---- prologue: stage tile 0 into buffer 0 ----
    f32x4 r0 = *(const f32x4*)(xsrc);
    f32x4 r1 = *(const f32x4*)(xsrc + 4);
    short8 rw = *(const short8*)(wsrc);
    *(short8*)(xa + sr * LDS_STRIDE + sby) = cvt8(r0, r1);
    *(short8*)(wb + sr * LDS_STRIDE + sby) = rw;
    __syncthreads();

    for (int k = 0; k < KSTEPS; ++k) {
        char* xcur = xa + (k & 1) * XTILE;
        char* xnxt = xa + ((k & 1) ^ 1) * XTILE;
        char* wcur = wb + (k & 1) * WTILE;
        char* wnxt = wb + ((k & 1) ^ 1) * WTILE;
        const int kt = (k + 1) * BK;

        // issue next tile's global loads (in flight during compute)
        if (k < KSTEPS - 1) {
            r0 = *(const f32x4*)(xsrc + kt);
            r1 = *(const f32x4*)(xsrc + kt + 4);
            rw = *(const short8*)(wsrc + kt);
        }

        // compute current tile: 2x4 frags, 8 MFMA
        short8 af[2], bfv[4];
#pragma unroll
        for (int m = 0; m < 2; ++m) {
            const int r = wrow + m * 16 + frow;
            af[m] = *(const short8*)(xcur + r * LDS_STRIDE + kg * 2);
        }
#pragma unroll
        for (int n = 0; n < 4; ++n) {
            const int r = wcol + n * 16 + frow;
            bfv[n] = *(const short8*)(wcur + r * LDS_STRIDE + kg * 2);
        }
#pragma unroll
        for (int m = 0; m < 2; ++m)
#pragma unroll
            for (int n = 0; n < 4; ++n)
                acc[m][n] = __builtin_amdgcn_mfma_f32_16x16x32_bf16(
                    af[m], bfv[n], acc[m][n], 0, 0, 0);

        // stage next tile into alternate buffer
        if (k < KSTEPS - 1) {
            *(short8*)(xnxt + sr * LDS_STRIDE + sby) = cvt8(r0, r1);
            *(short8*)(wnxt + sr * LDS_STRIDE + sby) = rw;
        }
        __syncthreads();
    }

    // epilogue: bias + relu + store (C/D: col=lane&15, row=(lane>>4)*4+reg)
    float bv[4];
#pragma unroll
    for (int n = 0; n < 4; ++n) bv[n] = bias[wcol + n * 16 + frow];
    const int colb = wcol + frow;
    const long grow = ((wrow < 64) ? (row0f + wrow) : (row0s + wrow - 64))
                      + ((lane >> 4) * 4);
#pragma unroll
    for (int m = 0; m < 2; ++m)
#pragma unroll
        for (int j = 0; j < 4; ++j) {
            float* orow = out + (grow + m * 16 + j) * N_DIM;
#pragma unroll
            for (int n = 0; n < 4; ++n)
                orow[colb + n * 16] = fmaxf(acc[m][n][j] + bv[n], 0.0f);
        }

    // ---- in-block MMD over the 32 pairs this block owns (L2-hot re-read) ---
    __threadfence_block();
    __syncthreads();

    const int pr  = tid >> 4;      // pair 0..31
    const int sub = tid & 15;      // 16 threads/pair, 8 dims each
    const float* r0p = out + (row0f + 2 * pr) * (long)N_DIM + sub * 8;  // s0
    const float* r1p = r0p + N_DIM;                                     // s1
    const float* r2p = out + (row0s + 2 * pr) * (long)N_DIM + sub * 8;  // t0
    const float* r3p = r2p + N_DIM;                                     // t1

    f32x4 vss = (f32x4)(0.f), vtt = (f32x4)(0.f), vst = (f32x4)(0.f), vts = (f32x4)(0.f);
#pragma unroll
    for (int c = 0; c < 2; ++c) {
        f32x4 a0 = *(const f32x4*)(r0p + 4 * c);
        f32x4 a1 = *(const f32x4*)(r1p + 4 * c);
        f32x4 b0 = *(const f32x4*)(r2p + 4 * c);
        f32x4 b1 = *(const f32x4*)(r3p + 4 * c);
        f32x4 d;
        d = a0 - a1; vss += d * d;
        d = b0 - b1; vtt += d * d;
        d = a0 - b1; vst += d * d;
        d = a1 - b0; vts += d * d;
    }
    float D[4];
    D[0] = vss[0] + vss[1] + vss[2] + vss[3];
    D[1] = vtt[0] + vtt[1] + vtt[2] + vtt[3];
    D[2] = vst[0] + vst[1] + vst[2] + vst[3];
    D[3] = vts[0] + vts[1] + vts[2] + vts[3];
#pragma unroll
    for (int off = 1; off <= 8; off <<= 1) {
#pragma unroll
        for (int i = 0; i < 4; ++i) D[i] += __shfl_xor(D[i], off, 64);
    }
    // 32 signed exp terms spread over the 16 threads of the pair (2 each)
    float part = 0.f;
#pragma unroll
    for (int j = 0; j < 2; ++j) {
        const int t  = sub * 2 + j;      // 0..31
        const int di = t >> 3;           // distance index 0..3
        const float invg = 16.0f / (float)(1 << (t & 7));   // 1/gamma_k
        const float e = __expf(-D[di] * invg);
        part += (di < 2) ? e : -e;
    }
#pragma unroll
    for (int off = 1; off <= 8; off <<= 1) part += __shfl_xor(part, off, 64);
    if (sub == 0) gsh[pr] = part * 0.125f;
    __syncthreads();
    if (tid == 0) {
        double s = 0.0;
#pragma unroll
        for (int i = 0; i < 32; ++i) s += (double)gsh[i];
        partials[blk] = s;
    }
}

__global__ void __launch_bounds__(256) mmd_reduce_kernel(
    const double* __restrict__ partials, float* __restrict__ loss)
{
    __shared__ double sd[256];
    const int tid = threadIdx.x;
    double s = 0.0;
    for (int i = tid; i < GBLOCKS; i += 256) s += partials[i];
    sd[tid] = s;
    __syncthreads();
    for (int w = 128; w; w >>= 1) {
        if (tid < w) sd[tid] += sd[tid + w];
        __syncthreads();
    }
    if (tid == 0) loss[0] = (float)(sd[0] * (2.0 / 65536.0));
}

extern "C" void kernel_launch(void* const* d_in, const int* in_sizes, int n_in,
                              void* d_out, int out_size, void* d_ws, size_t ws_size,
                              hipStream_t stream) {
    const float* x = (const float*)d_in[0];
    const float* W = (const float*)d_in[1];
    const float* b = (const float*)d_in[2];
    float* out = (float*)d_out;                         // 131072*128 + 1 floats

    __hip_bfloat16* Wt = (__hip_bfloat16*)d_ws;                 // 128 KB
    double* partials = (double*)((char*)d_ws + 131072);         // 8 KB

    wt_prep_kernel<<<256, 256, 0, stream>>>(W, Wt);
    gemm_relu_mmd_kernel<<<GBLOCKS, 512, 0, stream>>>(x, Wt, b, out, partials);
    mmd_reduce_kernel<<<1, 256, 0, stream>>>(partials, out + (long)M_TOTAL * N_DIM);
}